// Round 1
// baseline (836.795 us; speedup 1.0000x reference)
//
#include <hip/hip_runtime.h>
#include <stdint.h>

// Problem constants (B=64, P=24564, 21 classes)
#define NC 21
#define BATCH 64
#define PRI 24564
#define NROWS (BATCH * PRI)      // 1,572,096 (divisible by 256)
#define NBLK (NROWS / 256)       // 6141

__device__ __forceinline__ float sl1f(float p, float t) {
    float d = fabsf(p - t);
    return d < 1.0f ? 0.5f * d * d : d - 0.5f;
}

// monotonic float -> uint key map (order-preserving for all finite floats)
__device__ __forceinline__ unsigned int f2k(float v) {
    unsigned int u = __float_as_uint(v);
    return (u & 0x80000000u) ? ~u : (u | 0x80000000u);
}

// 256-thread block reduce (4 waves of 64). Valid result on tid==0.
__device__ __forceinline__ double blockReduce(double v, double* sred) {
    #pragma unroll
    for (int off = 32; off > 0; off >>= 1)
        v += __shfl_down(v, off, 64);
    const int wid = threadIdx.x >> 6, lane = threadIdx.x & 63;
    __syncthreads();                 // protect sred reuse across calls
    if (lane == 0) sred[wid] = v;
    __syncthreads();
    double r = 0.0;
    if (threadIdx.x == 0) r = sred[0] + sred[1] + sred[2] + sred[3];
    return r;
}

// Pass 1: per-row CE -> ws_ce, smooth-L1 partial sums, per-batch num_pos.
__global__ __launch_bounds__(256) void k_main(
    const float* __restrict__ loc_data, const float* __restrict__ conf_data,
    const float* __restrict__ size_lp_data, const float* __restrict__ offset_data,
    const float* __restrict__ loc_t, const int* __restrict__ conf_t,
    const int* __restrict__ has_lp_t, const float* __restrict__ size_lp_t,
    const float* __restrict__ offset_t,
    float* __restrict__ ws_ce, int* __restrict__ numpos, double* __restrict__ acc)
{
    __shared__ float sconf[256 * NC];
    __shared__ double sred[4];
    __shared__ int snp[2];
    const int tid = threadIdx.x;
    const long rowBase = (long)blockIdx.x * 256;

    // coalesced stage of 256 rows x 21 logits
    const float* src = conf_data + rowBase * NC;
    for (int k = tid; k < 256 * NC; k += 256) sconf[k] = src[k];
    if (tid < 2) snp[tid] = 0;
    __syncthreads();

    const long r = rowBase + tid;
    const int c = conf_t[r];
    const bool pos = c > 0;
    const int hl = has_lp_t[r];

    float ll = 0.f, ls = 0.f, lo = 0.f;
    if (pos) {
        float4 p = ((const float4*)loc_data)[r];
        float4 t = ((const float4*)loc_t)[r];
        ll = sl1f(p.x, t.x) + sl1f(p.y, t.y) + sl1f(p.z, t.z) + sl1f(p.w, t.w);
        if (hl != 0) {
            float2 sp = ((const float2*)size_lp_data)[r];
            float2 st = ((const float2*)size_lp_t)[r];
            ls = sl1f(sp.x, st.x) + sl1f(sp.y, st.y);
            float2 op = ((const float2*)offset_data)[r];
            float2 ot = ((const float2*)offset_t)[r];
            lo = sl1f(op.x, ot.x) + sl1f(op.y, ot.y);
        }
    }

    // 21-class CE: lse - logit[label]  (row stride 21 is odd -> <=2-way LDS aliasing, free)
    const float* row = sconf + tid * NC;
    float m = row[0];
    #pragma unroll
    for (int k = 1; k < NC; ++k) m = fmaxf(m, row[k]);
    float s = 0.f;
    #pragma unroll
    for (int k = 0; k < NC; ++k) s += expf(row[k] - m);
    const float ce = m + logf(s) - row[c];
    ws_ce[r] = ce;

    // per-batch num_pos (a block spans at most 2 batch rows since 256 < P)
    const int b0 = (int)(rowBase / PRI);
    const int b  = (int)(r / PRI);
    if (pos) atomicAdd(&snp[b - b0], 1);
    __syncthreads();
    if (tid < 2 && snp[tid] > 0) atomicAdd(&numpos[b0 + tid], snp[tid]);

    double v;
    v = blockReduce((double)ll, sred); if (tid == 0) atomicAdd(&acc[0], v);
    v = blockReduce((double)ls, sred); if (tid == 0) atomicAdd(&acc[2], v);
    v = blockReduce((double)lo, sred); if (tid == 0) atomicAdd(&acc[3], v);
}

// Pass 2: per batch row, exact top-K selection threshold via MSB radix select
// (K = min(3*num_pos, P-1)); ties broken by index -> find cutoff index of the
// needed-th equal element (matches stable argsort semantics).
__global__ __launch_bounds__(256) void k_select(
    const float* __restrict__ ws_ce, const int* __restrict__ conf_t,
    const int* __restrict__ numpos, unsigned int* __restrict__ Tb,
    int* __restrict__ cutoff)
{
    const int b = blockIdx.x;
    const int tid = threadIdx.x;
    const long base = (long)b * PRI;
    const int npos = numpos[b];
    int K = 3 * npos; if (K > PRI - 1) K = PRI - 1;
    if (K <= 0) {
        if (tid == 0) { Tb[b] = 0xFFFFFFFFu; cutoff[b] = -1; }
        return;
    }

    __shared__ int hist[256];
    __shared__ int s_dig, s_rem;
    __shared__ int wtot[4];
    __shared__ int s_run, s_found;

    unsigned int prefix = 0;
    int remaining = K;
    for (int round = 0; round < 4; ++round) {
        const int shift = 24 - 8 * round;
        hist[tid] = 0;
        __syncthreads();
        for (int p = tid; p < PRI; p += 256) {
            const int c = conf_t[base + p];
            const float v = (c > 0) ? 0.0f : ws_ce[base + p];  // ce_mine
            const unsigned int k = f2k(v);
            const bool match = (round == 0) || ((k >> (shift + 8)) == prefix);
            if (match) atomicAdd(&hist[(k >> shift) & 0xFF], 1);
        }
        __syncthreads();
        if (tid == 0) {
            int cum = 0;
            for (int d = 255; d >= 0; --d) {
                const int h = hist[d];
                if (cum + h >= remaining) { s_dig = d; s_rem = remaining - cum; break; }
                cum += h;
            }
        }
        __syncthreads();
        prefix = (prefix << 8) | (unsigned int)s_dig;
        remaining = s_rem;
        __syncthreads();   // hist reused next round
    }
    const unsigned int T = prefix;
    const int needed = remaining;  // >= 1; # of tied elements (lowest index first) selected

    if (tid == 0) { s_run = 0; s_found = -1; }
    __syncthreads();
    for (int cs = 0; cs < PRI; cs += 256) {
        const int p = cs + tid;
        bool eq = false;
        if (p < PRI) {
            const int c = conf_t[base + p];
            const float v = (c > 0) ? 0.0f : ws_ce[base + p];
            eq = (f2k(v) == T);
        }
        const unsigned long long mask = __ballot(eq);
        const int lane = tid & 63, wid = tid >> 6;
        if (lane == 0) wtot[wid] = __popcll(mask);
        const int myExcl = __popcll(mask & ((1ull << lane) - 1ull));
        __syncthreads();
        int woff = 0;
        for (int w = 0; w < wid; ++w) woff += wtot[w];
        if (eq && (s_run + woff + myExcl + 1 == needed)) s_found = p;
        __syncthreads();
        if (tid == 0) s_run += wtot[0] + wtot[1] + wtot[2] + wtot[3];
        __syncthreads();
        if (s_found >= 0) break;
    }
    if (tid == 0) { Tb[b] = T; cutoff[b] = s_found; }
}

// Pass 3: selection mask -> conf CE sum + has_lp 2-class CE sum.
__global__ __launch_bounds__(256) void k_conf(
    const float* __restrict__ ws_ce, const int* __restrict__ conf_t,
    const float* __restrict__ has_lp_data, const int* __restrict__ has_lp_t,
    const unsigned int* __restrict__ Tb, const int* __restrict__ cutoff,
    double* __restrict__ acc)
{
    __shared__ double sred[4];
    const int tid = threadIdx.x;
    const long r = (long)blockIdx.x * 256 + tid;
    const int b = (int)(r / PRI);
    const int p = (int)(r - (long)b * PRI);
    const int c = conf_t[r];
    const bool pos = c > 0;
    const float cev = ws_ce[r];
    const unsigned int k = pos ? 0x80000000u : f2k(cev);  // f2k(0.0f)==0x80000000
    const unsigned int T = Tb[b];
    const bool sel = pos || (k > T) || (k == T && p <= cutoff[b]);

    double lc = 0.0, lh = 0.0;
    if (sel) {
        lc = (double)cev;
        const float2 h = ((const float2*)has_lp_data)[r];
        const int ht = has_lp_t[r];
        const float m = fmaxf(h.x, h.y);
        const float s = expf(h.x - m) + expf(h.y - m);
        const float lse = m + logf(s);
        lh = (double)(lse - (ht != 0 ? h.y : h.x));
    }
    double v;
    v = blockReduce(lc, sred); if (tid == 0) atomicAdd(&acc[1], v);
    v = blockReduce(lh, sred); if (tid == 0) atomicAdd(&acc[4], v);
}

// Pass 4: divide by N and emit the 5 outputs.
__global__ void k_final(const double* __restrict__ acc,
                        const int* __restrict__ numpos, float* __restrict__ out)
{
    if (threadIdx.x == 0) {
        int N = 0;
        for (int i = 0; i < BATCH; ++i) N += numpos[i];
        const double dn = (double)N;
        out[0] = (float)(acc[0] / dn);   // loss_l
        out[1] = (float)(acc[1] / dn);   // loss_c
        out[2] = (float)(acc[2] / dn);   // loss_size_lp
        out[3] = (float)(acc[3] / dn);   // loss_offset
        out[4] = (float)(acc[4] / dn);   // loss_has_lp
    }
}

extern "C" void kernel_launch(void* const* d_in, const int* in_sizes, int n_in,
                              void* d_out, int out_size, void* d_ws, size_t ws_size,
                              hipStream_t stream)
{
    const float* loc_data     = (const float*)d_in[0];
    const float* conf_data    = (const float*)d_in[1];
    const float* has_lp_data  = (const float*)d_in[2];
    const float* size_lp_data = (const float*)d_in[3];
    const float* offset_data  = (const float*)d_in[4];
    const float* loc_t        = (const float*)d_in[5];
    const int*   conf_t       = (const int*)d_in[6];
    const int*   has_lp_t     = (const int*)d_in[7];
    const float* size_lp_t    = (const float*)d_in[8];
    const float* offset_t     = (const float*)d_in[9];
    float* out = (float*)d_out;

    char* ws = (char*)d_ws;
    double* acc        = (double*)ws;                 // 5 doubles  @ 0
    int* numpos        = (int*)(ws + 64);             // 64 ints    @ 64
    unsigned int* Tb   = (unsigned int*)(ws + 320);   // 64 uints   @ 320
    int* cutoff        = (int*)(ws + 576);            // 64 ints    @ 576
    float* ws_ce       = (float*)(ws + 1024);         // B*P floats @ 1024 (~6.3 MB)

    hipMemsetAsync(d_ws, 0, 1024, stream);  // zero accumulators + numpos (ws is poisoned 0xAA)

    k_main<<<NBLK, 256, 0, stream>>>(loc_data, conf_data, size_lp_data, offset_data,
                                     loc_t, conf_t, has_lp_t, size_lp_t, offset_t,
                                     ws_ce, numpos, acc);
    k_select<<<BATCH, 256, 0, stream>>>(ws_ce, conf_t, numpos, Tb, cutoff);
    k_conf<<<NBLK, 256, 0, stream>>>(ws_ce, conf_t, has_lp_data, has_lp_t, Tb, cutoff, acc);
    k_final<<<1, 64, 0, stream>>>(acc, numpos, out);
}

// Round 2
// 420.739 us; speedup vs baseline: 1.9889x; 1.9889x over previous
//
#include <hip/hip_runtime.h>
#include <stdint.h>

// Problem constants (B=64, P=24564, 21 classes)
#define NC 21
#define BATCH 64
#define PRI 24564
#define NROWS (BATCH * PRI)   // 1,572,096 = 2047 * 768
#define MBLK 2047             // blocks for k_main / k_conf
#define RPB 768               // rows per block (3 iterations of 256 threads)

// float4 with 4-byte alignment (conf rows are 84B-strided, only dword-aligned)
typedef float f4a4 __attribute__((ext_vector_type(4), aligned(4)));

__device__ __forceinline__ float sl1f(float p, float t) {
    float d = fabsf(p - t);
    return d < 1.0f ? 0.5f * d * d : d - 0.5f;
}

// monotonic float -> uint key map (order-preserving)
__device__ __forceinline__ unsigned int f2k(float v) {
    unsigned int u = __float_as_uint(v);
    return (u & 0x80000000u) ? ~u : (u | 0x80000000u);
}

// 256-thread block reduce (4 waves of 64). Valid on tid==0 only.
__device__ __forceinline__ double blockReduce(double v, double* sred) {
    #pragma unroll
    for (int off = 32; off > 0; off >>= 1)
        v += __shfl_down(v, off, 64);
    const int wid = threadIdx.x >> 6, lane = threadIdx.x & 63;
    __syncthreads();
    if (lane == 0) sred[wid] = v;
    __syncthreads();
    double r = 0.0;
    if (threadIdx.x == 0) r = sred[0] + sred[1] + sred[2] + sred[3];
    return r;
}

// Pass 1: per-row conf CE + has_lp CE -> packed ws_ch; smooth-L1 partials; num_pos.
__global__ __launch_bounds__(256) void k_main(
    const float* __restrict__ loc_data, const float* __restrict__ conf_data,
    const float* __restrict__ has_lp_data, const float* __restrict__ size_lp_data,
    const float* __restrict__ offset_data, const float* __restrict__ loc_t,
    const int* __restrict__ conf_t, const int* __restrict__ has_lp_t,
    const float* __restrict__ size_lp_t, const float* __restrict__ offset_t,
    float2* __restrict__ ws_ch, int* __restrict__ numpos, double* __restrict__ part)
{
    __shared__ double sred[4];
    __shared__ int snp[2];
    const int tid = threadIdx.x;
    if (tid < 2) snp[tid] = 0;
    __syncthreads();

    const int row0 = blockIdx.x * RPB;
    const int b0 = row0 / PRI;   // block spans at most 2 batch rows (768 < PRI)
    double aL = 0.0, aS = 0.0, aO = 0.0;

    #pragma unroll
    for (int i = 0; i < 3; ++i) {
        const unsigned r = row0 + i * 256 + tid;
        const int c = conf_t[r];
        const bool pos = c > 0;
        const int hl = has_lp_t[r];

        // 21-class CE, direct global loads (contiguous 84B/row, all bytes consumed)
        const float* crow = conf_data + (long)r * NC;
        const f4a4* cr4 = (const f4a4*)crow;
        float row[NC];
        #pragma unroll
        for (int j = 0; j < 5; ++j) {
            f4a4 v = cr4[j];
            row[4*j+0] = v.x; row[4*j+1] = v.y; row[4*j+2] = v.z; row[4*j+3] = v.w;
        }
        row[20] = crow[20];
        float m = row[0];
        #pragma unroll
        for (int k = 1; k < NC; ++k) m = fmaxf(m, row[k]);
        float s = 0.f;
        #pragma unroll
        for (int k = 0; k < NC; ++k) s += __expf(row[k] - m);
        const float g = crow[c];                  // L1 hit; avoids dynamic reg indexing
        const float ce = m + __logf(s) - g;

        // smooth-L1 terms
        float4 lp = ((const float4*)loc_data)[r];
        float4 lt = ((const float4*)loc_t)[r];
        float ll = sl1f(lp.x, lt.x) + sl1f(lp.y, lt.y) + sl1f(lp.z, lt.z) + sl1f(lp.w, lt.w);
        float2 sp = ((const float2*)size_lp_data)[r];
        float2 st = ((const float2*)size_lp_t)[r];
        float ls = sl1f(sp.x, st.x) + sl1f(sp.y, st.y);
        float2 op = ((const float2*)offset_data)[r];
        float2 ot = ((const float2*)offset_t)[r];
        float lo = sl1f(op.x, ot.x) + sl1f(op.y, ot.y);
        const float pf = pos ? 1.f : 0.f;
        const float hf = (hl != 0) ? 1.f : 0.f;
        aL += (double)(pf * ll);
        aS += (double)(pf * hf * ls);
        aO += (double)(pf * hf * lo);

        // has_lp 2-class CE (>=0), pos flag packed in sign bit
        float2 h2 = ((const float2*)has_lp_data)[r];
        float hm = fmaxf(h2.x, h2.y);
        float hs = __expf(h2.x - hm) + __expf(h2.y - hm);
        float hlce = fmaxf(hm + __logf(hs) - (hl != 0 ? h2.y : h2.x), 0.0f);
        unsigned hb = __float_as_uint(hlce) | (pos ? 0x80000000u : 0u);
        ws_ch[r] = make_float2(ce, __uint_as_float(hb));

        if (pos) atomicAdd(&snp[(r / PRI) - b0], 1);
    }

    double v;
    v = blockReduce(aL, sred); if (tid == 0) part[0 * 2048 + blockIdx.x] = v;
    v = blockReduce(aS, sred); if (tid == 0) part[1 * 2048 + blockIdx.x] = v;
    v = blockReduce(aO, sred); if (tid == 0) part[2 * 2048 + blockIdx.x] = v;
    if (tid < 2 && snp[tid] > 0) atomicAdd(&numpos[b0 + tid], snp[tid]);
}

// Pass 2: per batch row, exact top-K threshold (MSB radix select over ce_mine keys)
// + stable-tie cutoff index. K = min(3*num_pos, P-1). 1024 threads/block.
__global__ __launch_bounds__(1024) void k_select(
    const float2* __restrict__ ws_ch, const int* __restrict__ numpos,
    unsigned int* __restrict__ Tb, int* __restrict__ cutoff)
{
    const int b = blockIdx.x, tid = threadIdx.x;
    const long base = (long)b * PRI;
    int K = 3 * numpos[b]; if (K > PRI - 1) K = PRI - 1;
    if (K <= 0) {
        if (tid == 0) { Tb[b] = 0xFFFFFFFFu; cutoff[b] = -1; }
        return;
    }

    __shared__ int hist[256];
    __shared__ int sc[256];
    __shared__ int wtot[16];
    __shared__ int s_dig, s_rem, s_run, s_found;

    unsigned prefix = 0;
    int remaining = K;
    for (int round = 0; round < 4; ++round) {
        const int shift = 24 - 8 * round;
        if (tid < 256) hist[tid] = 0;
        __syncthreads();
        for (int t = tid; t < PRI; t += 1024) {
            float2 ch = ws_ch[base + t];
            unsigned hb = __float_as_uint(ch.y);
            unsigned k = (hb & 0x80000000u) ? 0x80000000u : f2k(ch.x);  // pos -> key(0.0)
            bool match = (round == 0) || ((k >> (shift + 8)) == prefix);
            if (match) atomicAdd(&hist[(k >> shift) & 255], 1);
        }
        __syncthreads();
        if (tid < 256) sc[tid] = hist[tid];
        __syncthreads();
        // parallel suffix sum: sc[d] = sum_{e>=d} hist[e]
        #pragma unroll
        for (int off = 1; off < 256; off <<= 1) {
            int v2 = 0;
            if (tid < 256 && tid + off < 256) v2 = sc[tid + off];
            __syncthreads();
            if (tid < 256) sc[tid] += v2;
            __syncthreads();
        }
        if (tid < 256) {
            int Sd = sc[tid];
            int Sn = (tid < 255) ? sc[tid + 1] : 0;
            if (Sd >= remaining && Sn < remaining) { s_dig = tid; s_rem = remaining - Sn; }
        }
        __syncthreads();
        prefix = (prefix << 8) | (unsigned)s_dig;
        remaining = s_rem;
    }
    const unsigned T = prefix;
    const int needed = remaining;   // >=1: # tied elements taken, lowest index first

    if (tid == 0) { s_run = 0; s_found = -1; }
    __syncthreads();
    for (int cs = 0; cs < PRI; cs += 1024) {
        const int p = cs + tid;
        bool eq = false;
        if (p < PRI) {
            float2 ch = ws_ch[base + p];
            unsigned hb = __float_as_uint(ch.y);
            unsigned k = (hb & 0x80000000u) ? 0x80000000u : f2k(ch.x);
            eq = (k == T);
        }
        const unsigned long long mask = __ballot(eq);
        const int lane = tid & 63, wid = tid >> 6;
        if (lane == 0) wtot[wid] = __popcll(mask);
        const int myexcl = __popcll(mask & ((1ull << lane) - 1ull));
        __syncthreads();
        int woff = 0;
        for (int w = 0; w < wid; ++w) woff += wtot[w];
        if (eq && (s_run + woff + myexcl + 1 == needed)) s_found = p;
        __syncthreads();
        if (tid == 0) { int tot = 0; for (int w = 0; w < 16; ++w) tot += wtot[w]; s_run += tot; }
        __syncthreads();
        if (s_found >= 0) break;
    }
    if (tid == 0) { Tb[b] = T; cutoff[b] = s_found; }
}

// Pass 3: selection mask -> conf CE sum + has_lp CE sum (reads only ws_ch).
__global__ __launch_bounds__(256) void k_conf(
    const float2* __restrict__ ws_ch, const unsigned int* __restrict__ Tb,
    const int* __restrict__ cutoff, double* __restrict__ part)
{
    __shared__ double sred[4];
    const int tid = threadIdx.x;
    const int row0 = blockIdx.x * RPB;
    double aC = 0.0, aH = 0.0;
    #pragma unroll
    for (int i = 0; i < 3; ++i) {
        const unsigned r = row0 + i * 256 + tid;
        const unsigned bb = r / PRI;
        const int p = (int)(r - bb * PRI);
        float2 ch = ws_ch[r];
        unsigned hb = __float_as_uint(ch.y);
        const bool pos = (hb >> 31) != 0;
        const unsigned k = pos ? 0x80000000u : f2k(ch.x);
        const unsigned T = Tb[bb];
        const bool sel = pos || (k > T) || (k == T && p <= cutoff[bb]);
        if (sel) {
            aC += (double)ch.x;
            aH += (double)__uint_as_float(hb & 0x7fffffffu);
        }
    }
    double v;
    v = blockReduce(aC, sred); if (tid == 0) part[3 * 2048 + blockIdx.x] = v;
    v = blockReduce(aH, sred); if (tid == 0) part[4 * 2048 + blockIdx.x] = v;
}

// Pass 4: sum partials, divide by N, emit 5 outputs.
__global__ __launch_bounds__(256) void k_final(
    const double* __restrict__ part, const int* __restrict__ numpos,
    float* __restrict__ out)
{
    __shared__ double sred[4];
    const int tid = threadIdx.x;
    double s[5];
    #pragma unroll
    for (int k = 0; k < 5; ++k) {
        double a = 0.0;
        for (int t = tid; t < MBLK; t += 256) a += part[k * 2048 + t];
        s[k] = blockReduce(a, sred);
    }
    double n = (tid < BATCH) ? (double)numpos[tid] : 0.0;
    n = blockReduce(n, sred);
    if (tid == 0) {
        out[0] = (float)(s[0] / n);   // loss_l
        out[1] = (float)(s[3] / n);   // loss_c
        out[2] = (float)(s[1] / n);   // loss_size_lp
        out[3] = (float)(s[2] / n);   // loss_offset
        out[4] = (float)(s[4] / n);   // loss_has_lp
    }
}

extern "C" void kernel_launch(void* const* d_in, const int* in_sizes, int n_in,
                              void* d_out, int out_size, void* d_ws, size_t ws_size,
                              hipStream_t stream)
{
    const float* loc_data     = (const float*)d_in[0];
    const float* conf_data    = (const float*)d_in[1];
    const float* has_lp_data  = (const float*)d_in[2];
    const float* size_lp_data = (const float*)d_in[3];
    const float* offset_data  = (const float*)d_in[4];
    const float* loc_t        = (const float*)d_in[5];
    const int*   conf_t       = (const int*)d_in[6];
    const int*   has_lp_t     = (const int*)d_in[7];
    const float* size_lp_t    = (const float*)d_in[8];
    const float* offset_t     = (const float*)d_in[9];
    float* out = (float*)d_out;

    char* ws = (char*)d_ws;
    int* numpos      = (int*)ws;                      // 64 ints   @ 0
    unsigned* Tb     = (unsigned*)(ws + 256);         // 64 uints  @ 256
    int* cutoff      = (int*)(ws + 512);              // 64 ints   @ 512
    double* part     = (double*)(ws + 1024);          // 5*2048 doubles @ 1024 (81920B)
    float2* ws_ch    = (float2*)(ws + 82944);         // NROWS float2 (~12.6 MB)

    hipMemsetAsync(ws, 0, 256, stream);   // zero numpos only (rest written unconditionally)

    k_main<<<MBLK, 256, 0, stream>>>(loc_data, conf_data, has_lp_data, size_lp_data,
                                     offset_data, loc_t, conf_t, has_lp_t,
                                     size_lp_t, offset_t, ws_ch, numpos, part);
    k_select<<<BATCH, 1024, 0, stream>>>(ws_ch, numpos, Tb, cutoff);
    k_conf<<<MBLK, 256, 0, stream>>>(ws_ch, Tb, cutoff, part);
    k_final<<<1, 256, 0, stream>>>(part, numpos, out);
}

// Round 3
// 349.990 us; speedup vs baseline: 2.3909x; 1.2021x over previous
//
#include <hip/hip_runtime.h>
#include <stdint.h>

// Problem constants (B=64, P=24564, 21 classes)
#define NC 21
#define BATCH 64
#define PRI 24564
#define NROWS (BATCH * PRI)   // 1,572,096
#define SLABS 32              // slabs per batch row
#define SLABR 768             // rows per slab (last slab: 756 valid)
#define GBLK (BATCH * SLABS)  // 2048 grid-wide blocks

// float4 with 4-byte alignment (conf rows are 84B-strided, only dword-aligned)
typedef float f4a4 __attribute__((ext_vector_type(4), aligned(4)));

__device__ __forceinline__ float sl1f(float p, float t) {
    float d = fabsf(p - t);
    return d < 1.0f ? 0.5f * d * d : d - 0.5f;
}

// monotonic float -> uint key map (order-preserving)
__device__ __forceinline__ unsigned int f2k(float v) {
    unsigned int u = __float_as_uint(v);
    return (u & 0x80000000u) ? ~u : (u | 0x80000000u);
}

// selection key from packed (ce, hlce|posbit)
__device__ __forceinline__ unsigned int chkey(float2 ch) {
    unsigned hb = __float_as_uint(ch.y);
    return (hb & 0x80000000u) ? 0x80000000u : f2k(ch.x);  // pos -> f2k(0.0)
}

// 256-thread block reduce (4 waves of 64). Valid on tid==0 only.
__device__ __forceinline__ double blockReduce(double v, double* sred) {
    #pragma unroll
    for (int off = 32; off > 0; off >>= 1)
        v += __shfl_down(v, off, 64);
    const int wid = threadIdx.x >> 6, lane = threadIdx.x & 63;
    __syncthreads();
    if (lane == 0) sred[wid] = v;
    __syncthreads();
    double r = 0.0;
    if (threadIdx.x == 0) r = sred[0] + sred[1] + sred[2] + sred[3];
    return r;
}

// Pass 1: per-row conf CE + has_lp CE -> ws_ch; smooth-L1 partials; num_pos;
// fused round-1 radix histogram (top 12 key bits) into ghist1[b][4096].
__global__ __launch_bounds__(256) void k_main(
    const float* __restrict__ loc_data, const float* __restrict__ conf_data,
    const float* __restrict__ has_lp_data, const float* __restrict__ size_lp_data,
    const float* __restrict__ offset_data, const float* __restrict__ loc_t,
    const int* __restrict__ conf_t, const int* __restrict__ has_lp_t,
    const float* __restrict__ size_lp_t, const float* __restrict__ offset_t,
    float2* __restrict__ ws_ch, int* __restrict__ numpos, double* __restrict__ part,
    int* __restrict__ ghist1)
{
    __shared__ int hist[4096];
    __shared__ double sred[4];
    const int tid = threadIdx.x;
    const int b = blockIdx.x >> 5, s = blockIdx.x & 31;
    for (int k = tid; k < 4096; k += 256) hist[k] = 0;
    __syncthreads();

    double aL = 0.0, aS = 0.0, aO = 0.0;
    int myp = 0;

    #pragma unroll
    for (int i = 0; i < 3; ++i) {
        const int p = s * SLABR + i * 256 + tid;
        if (p < PRI) {
            const unsigned r = (unsigned)b * PRI + p;
            const int c = conf_t[r];
            const bool pos = c > 0;
            const int hl = has_lp_t[r];

            // 21-class CE, direct global loads
            const float* crow = conf_data + (long)r * NC;
            const f4a4* cr4 = (const f4a4*)crow;
            float row[NC];
            #pragma unroll
            for (int j = 0; j < 5; ++j) {
                f4a4 v = cr4[j];
                row[4*j+0] = v.x; row[4*j+1] = v.y; row[4*j+2] = v.z; row[4*j+3] = v.w;
            }
            row[20] = crow[20];
            float m = row[0];
            #pragma unroll
            for (int k = 1; k < NC; ++k) m = fmaxf(m, row[k]);
            float sum = 0.f;
            #pragma unroll
            for (int k = 0; k < NC; ++k) sum += __expf(row[k] - m);
            const float g = crow[c];
            const float ce = m + __logf(sum) - g;

            // smooth-L1 terms
            float4 lp = ((const float4*)loc_data)[r];
            float4 lt = ((const float4*)loc_t)[r];
            float ll = sl1f(lp.x, lt.x) + sl1f(lp.y, lt.y) + sl1f(lp.z, lt.z) + sl1f(lp.w, lt.w);
            float2 sp = ((const float2*)size_lp_data)[r];
            float2 st = ((const float2*)size_lp_t)[r];
            float ls = sl1f(sp.x, st.x) + sl1f(sp.y, st.y);
            float2 op = ((const float2*)offset_data)[r];
            float2 ot = ((const float2*)offset_t)[r];
            float lo = sl1f(op.x, ot.x) + sl1f(op.y, ot.y);
            const float pf = pos ? 1.f : 0.f;
            const float hf = (hl != 0) ? 1.f : 0.f;
            aL += (double)(pf * ll);
            aS += (double)(pf * hf * ls);
            aO += (double)(pf * hf * lo);

            // has_lp 2-class CE (>=0), pos flag packed in sign bit
            float2 h2 = ((const float2*)has_lp_data)[r];
            float hm = fmaxf(h2.x, h2.y);
            float hs = __expf(h2.x - hm) + __expf(h2.y - hm);
            float hlce = fmaxf(hm + __logf(hs) - (hl != 0 ? h2.y : h2.x), 0.0f);
            unsigned hb = __float_as_uint(hlce) | (pos ? 0x80000000u : 0u);
            ws_ch[r] = make_float2(ce, __uint_as_float(hb));

            const unsigned key = pos ? 0x80000000u : f2k(ce);
            atomicAdd(&hist[key >> 20], 1);
            myp += pos ? 1 : 0;
        }
    }

    double v;
    v = blockReduce(aL, sred); if (tid == 0) part[0 * GBLK + blockIdx.x] = v;
    v = blockReduce(aS, sred); if (tid == 0) part[1 * GBLK + blockIdx.x] = v;
    v = blockReduce(aO, sred); if (tid == 0) part[2 * GBLK + blockIdx.x] = v;
    v = blockReduce((double)myp, sred);
    if (tid == 0 && v > 0.0) atomicAdd(&numpos[b], (int)(v + 0.5));

    __syncthreads();
    for (int k = tid; k < 4096; k += 256) {
        int h = hist[k];
        if (h) atomicAdd(&ghist1[(b << 12) + k], h);
    }
}

// Digit pick per batch: parallel suffix-scan of the per-batch histogram.
// ROUND 0: NB=4096 (rem=K from numpos); ROUND 1: NB=1024; ROUND 2: NB=1024, final.
template<int NB, int ROUND>
__global__ __launch_bounds__(256) void k_pick(
    const int* __restrict__ ghist, const int* __restrict__ numpos,
    unsigned* __restrict__ prefix_io, int* __restrict__ rem_io,
    unsigned* __restrict__ selT, int* __restrict__ needed)
{
    const int b = blockIdx.x, tid = threadIdx.x;
    constexpr int CH = NB / 256;
    __shared__ int sct[256];
    __shared__ unsigned s_dig;
    __shared__ int s_rem;

    int rem;
    if (ROUND == 0) { int K = 3 * numpos[b]; if (K > PRI - 1) K = PRI - 1; rem = K; }
    else rem = rem_io[b];
    if (rem <= 0) {
        if (tid == 0) {
            prefix_io[b] = 0xFFFFFFFFu;
            rem_io[b] = 0;
            if (ROUND == 2) { selT[b] = 0xFFFFFFFFu; needed[b] = 0; }
        }
        return;
    }

    int h[CH];
    const int* g = ghist + b * NB + tid * CH;
    int ct = 0;
    #pragma unroll
    for (int j = 0; j < CH; ++j) { h[j] = g[j]; ct += h[j]; }
    sct[tid] = ct;
    __syncthreads();
    #pragma unroll
    for (int off = 1; off < 256; off <<= 1) {
        int v = (tid + off < 256) ? sct[tid + off] : 0;
        __syncthreads();
        sct[tid] += v;
        __syncthreads();
    }
    const int Safter = (tid < 255) ? sct[tid + 1] : 0;  // keys in chunks above mine
    int cum = Safter;
    #pragma unroll
    for (int j = CH - 1; j >= 0; --j) {  // walk bins high -> low
        int c2 = cum + h[j];
        if (c2 >= rem && cum < rem) { s_dig = (unsigned)(tid * CH + j); s_rem = rem - cum; }
        cum = c2;
    }
    __syncthreads();
    if (tid == 0) {
        unsigned d = s_dig;
        if (ROUND == 0)      { prefix_io[b] = d;                         rem_io[b] = s_rem; }
        else if (ROUND == 1) { prefix_io[b] = (prefix_io[b] << 10) | d;  rem_io[b] = s_rem; }
        else                 { selT[b]      = (prefix_io[b] << 10) | d;  needed[b] = s_rem; }
    }
}

// Refinement histogram round (grid-wide): bins = (key >> BSHIFT) & 1023 among
// rows whose (key >> MSHIFT) matches the batch prefix.
template<int MSHIFT, int BSHIFT>
__global__ __launch_bounds__(256) void k_hist(
    const float2* __restrict__ ws_ch, const unsigned* __restrict__ prefix_io,
    int* __restrict__ ghist)
{
    __shared__ int hist[1024];
    const int tid = threadIdx.x;
    const int b = blockIdx.x >> 5, s = blockIdx.x & 31;
    const unsigned pref = prefix_io[b];
    for (int k = tid; k < 1024; k += 256) hist[k] = 0;
    __syncthreads();
    #pragma unroll
    for (int i = 0; i < 3; ++i) {
        const int p = s * SLABR + i * 256 + tid;
        if (p < PRI) {
            unsigned key = chkey(ws_ch[(unsigned)b * PRI + p]);
            if ((key >> MSHIFT) == pref) atomicAdd(&hist[(key >> BSHIFT) & 1023], 1);
        }
    }
    __syncthreads();
    for (int k = tid; k < 1024; k += 256) {
        int h = hist[k];
        if (h) atomicAdd(&ghist[(b << 10) + k], h);
    }
}

// Per-slab count of key == T (for stable-tie cutoff).
__global__ __launch_bounds__(256) void k_cntslab(
    const float2* __restrict__ ws_ch, const unsigned* __restrict__ selT,
    int* __restrict__ scnt)
{
    __shared__ int c4[4];
    const int tid = threadIdx.x;
    const int b = blockIdx.x >> 5, s = blockIdx.x & 31;
    const unsigned T = selT[b];
    int my = 0;
    #pragma unroll
    for (int i = 0; i < 3; ++i) {
        const int p = s * SLABR + i * 256 + tid;
        if (p < PRI) my += (chkey(ws_ch[(unsigned)b * PRI + p]) == T) ? 1 : 0;
    }
    #pragma unroll
    for (int off = 32; off > 0; off >>= 1) my += __shfl_down(my, off, 64);
    if ((tid & 63) == 0) c4[tid >> 6] = my;
    __syncthreads();
    if (tid == 0) scnt[b * SLABS + s] = c4[0] + c4[1] + c4[2] + c4[3];
}

// Stable-tie cutoff: global index of the needed-th element with key == T.
__global__ __launch_bounds__(256) void k_cut(
    const float2* __restrict__ ws_ch, const int* __restrict__ scnt,
    const unsigned* __restrict__ selT, const int* __restrict__ needed,
    int* __restrict__ cutoff)
{
    const int b = blockIdx.x, tid = threadIdx.x;
    __shared__ int s_slab, s_local, s_found;
    __shared__ int wtot[4];
    const int need = needed[b];
    if (need <= 0) { if (tid == 0) cutoff[b] = -1; return; }
    if (tid == 0) {
        int cum = 0, sl = SLABS - 1, loc = need;
        for (int s2 = 0; s2 < SLABS; ++s2) {
            int c = scnt[b * SLABS + s2];
            if (cum + c >= need) { sl = s2; loc = need - cum; break; }
            cum += c;
        }
        s_slab = sl; s_local = loc; s_found = -1;
    }
    __syncthreads();
    const unsigned T = selT[b];
    const int s = s_slab, local = s_local;
    int run = 0;
    for (int i = 0; i < 3; ++i) {
        const int p = s * SLABR + i * 256 + tid;
        bool eq = false;
        if (p < PRI) eq = (chkey(ws_ch[(unsigned)b * PRI + p]) == T);
        const unsigned long long m = __ballot(eq);
        const int lane = tid & 63, wid = tid >> 6;
        if (lane == 0) wtot[wid] = __popcll(m);
        const int mex = __popcll(m & ((1ull << lane) - 1ull));
        __syncthreads();
        int woff = 0;
        for (int w = 0; w < wid; ++w) woff += wtot[w];
        if (eq && (run + woff + mex + 1 == local)) s_found = p;
        __syncthreads();
        run += wtot[0] + wtot[1] + wtot[2] + wtot[3];
        __syncthreads();   // protect wtot before next iteration's write
    }
    if (tid == 0) cutoff[b] = s_found;
}

// Selection mask -> conf CE sum + has_lp CE sum (reads only ws_ch).
__global__ __launch_bounds__(256) void k_conf(
    const float2* __restrict__ ws_ch, const unsigned* __restrict__ selT,
    const int* __restrict__ cutoff, double* __restrict__ part)
{
    __shared__ double sred[4];
    const int tid = threadIdx.x;
    const int b = blockIdx.x >> 5, s = blockIdx.x & 31;
    const unsigned T = selT[b];
    const int cut = cutoff[b];
    double aC = 0.0, aH = 0.0;
    #pragma unroll
    for (int i = 0; i < 3; ++i) {
        const int p = s * SLABR + i * 256 + tid;
        if (p < PRI) {
            float2 ch = ws_ch[(unsigned)b * PRI + p];
            unsigned hb = __float_as_uint(ch.y);
            const bool pos = (hb >> 31) != 0;
            const unsigned key = pos ? 0x80000000u : f2k(ch.x);
            const bool sel = pos || (key > T) || (key == T && p <= cut);
            if (sel) {
                aC += (double)ch.x;
                aH += (double)__uint_as_float(hb & 0x7fffffffu);
            }
        }
    }
    double v;
    v = blockReduce(aC, sred); if (tid == 0) part[3 * GBLK + blockIdx.x] = v;
    v = blockReduce(aH, sred); if (tid == 0) part[4 * GBLK + blockIdx.x] = v;
}

// Sum partials, divide by N, emit 5 outputs.
__global__ __launch_bounds__(256) void k_final(
    const double* __restrict__ part, const int* __restrict__ numpos,
    float* __restrict__ out)
{
    __shared__ double sred[4];
    const int tid = threadIdx.x;
    double s[5];
    #pragma unroll
    for (int k = 0; k < 5; ++k) {
        double a = 0.0;
        for (int t = tid; t < GBLK; t += 256) a += part[k * GBLK + t];
        s[k] = blockReduce(a, sred);
    }
    double n = (tid < BATCH) ? (double)numpos[tid] : 0.0;
    n = blockReduce(n, sred);
    if (tid == 0) {
        out[0] = (float)(s[0] / n);   // loss_l
        out[1] = (float)(s[3] / n);   // loss_c
        out[2] = (float)(s[1] / n);   // loss_size_lp
        out[3] = (float)(s[2] / n);   // loss_offset
        out[4] = (float)(s[4] / n);   // loss_has_lp
    }
}

extern "C" void kernel_launch(void* const* d_in, const int* in_sizes, int n_in,
                              void* d_out, int out_size, void* d_ws, size_t ws_size,
                              hipStream_t stream)
{
    const float* loc_data     = (const float*)d_in[0];
    const float* conf_data    = (const float*)d_in[1];
    const float* has_lp_data  = (const float*)d_in[2];
    const float* size_lp_data = (const float*)d_in[3];
    const float* offset_data  = (const float*)d_in[4];
    const float* loc_t        = (const float*)d_in[5];
    const int*   conf_t       = (const int*)d_in[6];
    const int*   has_lp_t     = (const int*)d_in[7];
    const float* size_lp_t    = (const float*)d_in[8];
    const float* offset_t     = (const float*)d_in[9];
    float* out = (float*)d_out;

    char* ws = (char*)d_ws;
    int* numpos        = (int*)(ws + 0);         // 64 ints
    unsigned* selT     = (unsigned*)(ws + 256);  // 64 u32
    int* cutoff        = (int*)(ws + 512);       // 64 ints
    unsigned* prefix   = (unsigned*)(ws + 768);  // 64 u32
    int* rem           = (int*)(ws + 1024);      // 64 ints
    int* needed        = (int*)(ws + 1280);      // 64 ints
    int* scnt          = (int*)(ws + 1536);      // 64*32 ints (8 KB)
    double* part       = (double*)(ws + 10240);  // 5*2048 doubles (80 KB)
    int* ghist1        = (int*)(ws + 92160);     // 64*4096 ints (1 MB)
    int* ghist2        = (int*)(ws + 1140736);   // 64*1024 ints (256 KB)
    int* ghist3        = (int*)(ws + 1402880);   // 64*1024 ints (256 KB)
    float2* ws_ch      = (float2*)(ws + 1665024);// NROWS float2 (~12.6 MB)

    hipMemsetAsync(ws, 0, 256, stream);                 // numpos
    hipMemsetAsync(ws + 92160, 0, 1572864, stream);     // ghist1..3

    k_main<<<GBLK, 256, 0, stream>>>(loc_data, conf_data, has_lp_data, size_lp_data,
                                     offset_data, loc_t, conf_t, has_lp_t,
                                     size_lp_t, offset_t, ws_ch, numpos, part, ghist1);
    k_pick<4096, 0><<<BATCH, 256, 0, stream>>>(ghist1, numpos, prefix, rem, selT, needed);
    k_hist<20, 10><<<GBLK, 256, 0, stream>>>(ws_ch, prefix, ghist2);
    k_pick<1024, 1><<<BATCH, 256, 0, stream>>>(ghist2, numpos, prefix, rem, selT, needed);
    k_hist<10, 0><<<GBLK, 256, 0, stream>>>(ws_ch, prefix, ghist3);
    k_pick<1024, 2><<<BATCH, 256, 0, stream>>>(ghist3, numpos, prefix, rem, selT, needed);
    k_cntslab<<<GBLK, 256, 0, stream>>>(ws_ch, selT, scnt);
    k_cut<<<BATCH, 256, 0, stream>>>(ws_ch, scnt, selT, needed, cutoff);
    k_conf<<<GBLK, 256, 0, stream>>>(ws_ch, selT, cutoff, part);
    k_final<<<1, 256, 0, stream>>>(part, numpos, out);
}

// Round 4
// 334.263 us; speedup vs baseline: 2.5034x; 1.0471x over previous
//
#include <hip/hip_runtime.h>
#include <stdint.h>

// Problem constants (B=64, P=24564, 21 classes)
#define NC 21
#define BATCH 64
#define PRI 24564
#define NROWS (BATCH * PRI)   // 1,572,096
#define SLABS 32              // slabs per batch row
#define SLABR 768             // rows per slab (last slab: 756 valid)
#define GBLK (BATCH * SLABS)  // 2048 grid-wide blocks
#define SENT 0xFFFFFFFFu      // "skip refinement" prefix sentinel

// float4 with 4-byte alignment (conf rows are 84B-strided, only dword-aligned)
typedef float f4a4 __attribute__((ext_vector_type(4), aligned(4)));

__device__ __forceinline__ float sl1f(float p, float t) {
    float d = fabsf(p - t);
    return d < 1.0f ? 0.5f * d * d : d - 0.5f;
}

// monotonic float -> uint key map (order-preserving)
__device__ __forceinline__ unsigned int f2k(float v) {
    unsigned int u = __float_as_uint(v);
    return (u & 0x80000000u) ? ~u : (u | 0x80000000u);
}

// selection key from packed (ce, hlce|posbit); pos -> f2k(0.0) = 0x80000000
__device__ __forceinline__ unsigned int chkey(float2 ch) {
    unsigned hb = __float_as_uint(ch.y);
    return (hb & 0x80000000u) ? 0x80000000u : f2k(ch.x);
}

// 256-thread block reduce (4 waves of 64). Valid on tid==0 only.
__device__ __forceinline__ double blockReduce(double v, double* sred) {
    #pragma unroll
    for (int off = 32; off > 0; off >>= 1)
        v += __shfl_down(v, off, 64);
    const int wid = threadIdx.x >> 6, lane = threadIdx.x & 63;
    __syncthreads();
    if (lane == 0) sred[wid] = v;
    __syncthreads();
    double r = 0.0;
    if (threadIdx.x == 0) r = sred[0] + sred[1] + sred[2] + sred[3];
    return r;
}

// Pass 1: per-row conf CE + has_lp CE -> ws_ch; smooth-L1 partials; num_pos;
// round-1 radix histogram (top 12 key bits) over NONZERO-key rows only.
// Loads for all 3 row-iterations issued before compute (MLP; VGPR target <=128).
__global__ __launch_bounds__(256, 4) void k_main(
    const float* __restrict__ loc_data, const float* __restrict__ conf_data,
    const float* __restrict__ has_lp_data, const float* __restrict__ size_lp_data,
    const float* __restrict__ offset_data, const float* __restrict__ loc_t,
    const int* __restrict__ conf_t, const int* __restrict__ has_lp_t,
    const float* __restrict__ size_lp_t, const float* __restrict__ offset_t,
    float2* __restrict__ ws_ch, int* __restrict__ numpos, double* __restrict__ part,
    int* __restrict__ ghist1)
{
    __shared__ int hist[4096];
    __shared__ double sred[4];
    const int tid = threadIdx.x;
    const int b = blockIdx.x >> 5, s = blockIdx.x & 31;
    for (int k = tid; k < 4096; k += 256) hist[k] = 0;
    __syncthreads();

    int pr[3]; bool vld[3];
    #pragma unroll
    for (int i = 0; i < 3; ++i) {
        int p = s * SLABR + i * 256 + tid;
        vld[i] = p < PRI;
        pr[i] = vld[i] ? p : PRI - 1;   // clamp: loads unconditional, safe
    }
    const unsigned rb = (unsigned)b * PRI;

    // ---------- phase A: 21-class conf CE ----------
    int ct[3];
    #pragma unroll
    for (int i = 0; i < 3; ++i) ct[i] = conf_t[rb + pr[i]];
    f4a4 cw[3][5]; float c20[3], gg[3];
    #pragma unroll
    for (int i = 0; i < 3; ++i) {
        const float* crow = conf_data + (long)(rb + pr[i]) * NC;
        #pragma unroll
        for (int j = 0; j < 5; ++j) cw[i][j] = ((const f4a4*)crow)[j];
        c20[i] = crow[20];
        gg[i] = crow[ct[i]];
    }
    float ce[3];
    #pragma unroll
    for (int i = 0; i < 3; ++i) {
        float m = c20[i];
        #pragma unroll
        for (int j = 0; j < 5; ++j)
            m = fmaxf(m, fmaxf(fmaxf(cw[i][j].x, cw[i][j].y), fmaxf(cw[i][j].z, cw[i][j].w)));
        float sum = __expf(c20[i] - m);
        #pragma unroll
        for (int j = 0; j < 5; ++j)
            sum += __expf(cw[i][j].x - m) + __expf(cw[i][j].y - m)
                 + __expf(cw[i][j].z - m) + __expf(cw[i][j].w - m);
        ce[i] = m + __logf(sum) - gg[i];
    }
    // histogram only nonzero-key rows (negatives with ce != +0): no contention
    #pragma unroll
    for (int i = 0; i < 3; ++i) {
        if (vld[i] && ct[i] <= 0) {
            unsigned key = f2k(ce[i]);
            if (key != 0x80000000u) atomicAdd(&hist[key >> 20], 1);
        }
    }

    // ---------- phase B: smooth-L1 + has_lp CE ----------
    int hl[3]; float4 lp[3], lt[3]; float2 sp2[3], st2[3], op2[3], ot2[3], hh[3];
    #pragma unroll
    for (int i = 0; i < 3; ++i) {
        const unsigned r = rb + pr[i];
        hl[i] = has_lp_t[r];
        lp[i] = ((const float4*)loc_data)[r];
        lt[i] = ((const float4*)loc_t)[r];
        sp2[i] = ((const float2*)size_lp_data)[r];
        st2[i] = ((const float2*)size_lp_t)[r];
        op2[i] = ((const float2*)offset_data)[r];
        ot2[i] = ((const float2*)offset_t)[r];
        hh[i] = ((const float2*)has_lp_data)[r];
    }
    double aL = 0.0, aS = 0.0, aO = 0.0;
    int myp = 0;
    #pragma unroll
    for (int i = 0; i < 3; ++i) {
        const bool pos = ct[i] > 0;
        float ll = sl1f(lp[i].x, lt[i].x) + sl1f(lp[i].y, lt[i].y)
                 + sl1f(lp[i].z, lt[i].z) + sl1f(lp[i].w, lt[i].w);
        float ls = sl1f(sp2[i].x, st2[i].x) + sl1f(sp2[i].y, st2[i].y);
        float lo = sl1f(op2[i].x, ot2[i].x) + sl1f(op2[i].y, ot2[i].y);
        const float pf = (vld[i] && pos) ? 1.f : 0.f;
        const float hf = (hl[i] != 0) ? 1.f : 0.f;
        aL += (double)(pf * ll);
        aS += (double)(pf * hf * ls);
        aO += (double)(pf * hf * lo);
        float hm = fmaxf(hh[i].x, hh[i].y);
        float hs = __expf(hh[i].x - hm) + __expf(hh[i].y - hm);
        float hlce = fmaxf(hm + __logf(hs) - (hl[i] != 0 ? hh[i].y : hh[i].x), 0.0f);
        unsigned hb = __float_as_uint(hlce) | (pos ? 0x80000000u : 0u);
        if (vld[i]) ws_ch[rb + pr[i]] = make_float2(ce[i], __uint_as_float(hb));
        myp += (vld[i] && pos) ? 1 : 0;
    }

    double v;
    v = blockReduce(aL, sred); if (tid == 0) part[0 * GBLK + blockIdx.x] = v;
    v = blockReduce(aS, sred); if (tid == 0) part[1 * GBLK + blockIdx.x] = v;
    v = blockReduce(aO, sred); if (tid == 0) part[2 * GBLK + blockIdx.x] = v;
    v = blockReduce((double)myp, sred);
    if (tid == 0 && v > 0.0) atomicAdd(&numpos[b], (int)(v + 0.5));

    __syncthreads();
    for (int k = tid; k < 4096; k += 256) {
        int h = hist[k];
        if (h) atomicAdd(&ghist1[(b << 12) + k], h);
    }
}

// Round-0 digit pick + mode decision. M = # nonzero-key rows in batch.
// K > M  -> T = key(0), needed = K - M, refinement skipped (sentinel prefix).
// K <= M -> normal radix digit pick on top-12 bits.
__global__ __launch_bounds__(256) void k_pick0(
    const int* __restrict__ ghist1, const int* __restrict__ numpos,
    unsigned* __restrict__ prefix_io, int* __restrict__ rem_io,
    unsigned* __restrict__ selT, int* __restrict__ needed)
{
    const int b = blockIdx.x, tid = threadIdx.x;
    __shared__ int sct[256];
    __shared__ unsigned s_dig;
    __shared__ int s_rem;

    int K = 3 * numpos[b]; if (K > PRI - 1) K = PRI - 1;

    int h[16];
    const int* g = ghist1 + (b << 12) + tid * 16;
    int ctn = 0;
    #pragma unroll
    for (int j = 0; j < 16; ++j) { h[j] = g[j]; ctn += h[j]; }
    sct[tid] = ctn;
    __syncthreads();
    #pragma unroll
    for (int off = 1; off < 256; off <<= 1) {
        int v = (tid + off < 256) ? sct[tid + off] : 0;
        __syncthreads();
        sct[tid] += v;
        __syncthreads();
    }
    const int M = sct[0];

    if (K <= 0) {
        if (tid == 0) { selT[b] = 0xFFFFFFFFu; needed[b] = 0; rem_io[b] = 0; prefix_io[b] = SENT; }
        return;
    }
    if (K > M) {   // threshold sits in the zero-key (ce_mine == 0) population
        if (tid == 0) { selT[b] = 0x80000000u; needed[b] = K - M; rem_io[b] = 0; prefix_io[b] = SENT; }
        return;
    }
    const int Safter = (tid < 255) ? sct[tid + 1] : 0;
    int cum = Safter;
    #pragma unroll
    for (int j = 15; j >= 0; --j) {
        int c2 = cum + h[j];
        if (c2 >= K && cum < K) { s_dig = (unsigned)(tid * 16 + j); s_rem = K - cum; }
        cum = c2;
    }
    __syncthreads();
    if (tid == 0) { prefix_io[b] = s_dig; rem_io[b] = s_rem; }
}

// Refinement histogram (grid-wide, 1024 bins). Nulls out on sentinel prefix.
// Zero-key rows excluded (consistent with ghist1).
template<int MSHIFT, int BSHIFT>
__global__ __launch_bounds__(256) void k_hist(
    const float2* __restrict__ ws_ch, const unsigned* __restrict__ prefix_io,
    int* __restrict__ ghist)
{
    const int b = blockIdx.x >> 5, s = blockIdx.x & 31;
    const unsigned pref = prefix_io[b];
    if (pref == SENT) return;
    __shared__ int hist[1024];
    const int tid = threadIdx.x;
    for (int k = tid; k < 1024; k += 256) hist[k] = 0;
    __syncthreads();
    #pragma unroll
    for (int i = 0; i < 3; ++i) {
        const int p = s * SLABR + i * 256 + tid;
        if (p < PRI) {
            unsigned key = chkey(ws_ch[(unsigned)b * PRI + p]);
            if (key != 0x80000000u && (key >> MSHIFT) == pref)
                atomicAdd(&hist[(key >> BSHIFT) & 1023], 1);
        }
    }
    __syncthreads();
    for (int k = tid; k < 1024; k += 256) {
        int h = hist[k];
        if (h) atomicAdd(&ghist[(b << 10) + k], h);
    }
}

// Refinement digit pick (1024 bins). ROUND 1 mid, ROUND 2 final.
template<int ROUND>
__global__ __launch_bounds__(256) void k_pickR(
    const int* __restrict__ ghist, unsigned* __restrict__ prefix_io,
    int* __restrict__ rem_io, unsigned* __restrict__ selT, int* __restrict__ needed)
{
    const int b = blockIdx.x, tid = threadIdx.x;
    const int rem = rem_io[b];
    if (rem <= 0) return;   // skipped (mode decided in pick0) — touch nothing
    __shared__ int sct[256];
    __shared__ unsigned s_dig;
    __shared__ int s_rem;
    int h[4];
    const int* g = ghist + (b << 10) + tid * 4;
    int ctn = 0;
    #pragma unroll
    for (int j = 0; j < 4; ++j) { h[j] = g[j]; ctn += h[j]; }
    sct[tid] = ctn;
    __syncthreads();
    #pragma unroll
    for (int off = 1; off < 256; off <<= 1) {
        int v = (tid + off < 256) ? sct[tid + off] : 0;
        __syncthreads();
        sct[tid] += v;
        __syncthreads();
    }
    const int Safter = (tid < 255) ? sct[tid + 1] : 0;
    int cum = Safter;
    #pragma unroll
    for (int j = 3; j >= 0; --j) {
        int c2 = cum + h[j];
        if (c2 >= rem && cum < rem) { s_dig = (unsigned)(tid * 4 + j); s_rem = rem - cum; }
        cum = c2;
    }
    __syncthreads();
    if (tid == 0) {
        if (ROUND == 1) { prefix_io[b] = (prefix_io[b] << 10) | s_dig; rem_io[b] = s_rem; }
        else            { selT[b] = (prefix_io[b] << 10) | s_dig;      needed[b] = s_rem; }
    }
}

// Per-slab: tie count (key==T, all rows) + selected-core sums (pos || key>T)
// + tie-negative sums (per-slab, for cutoff accounting). One pass over ws_ch.
__global__ __launch_bounds__(256) void k_sel2(
    const float2* __restrict__ ws_ch, const unsigned* __restrict__ selT,
    int* __restrict__ cntT, double* __restrict__ sums)
{
    __shared__ double sred[4];
    const int tid = threadIdx.x;
    const int b = blockIdx.x >> 5, s = blockIdx.x & 31;
    const unsigned T = selT[b];
    double aC = 0.0, aH = 0.0, tC = 0.0, tH = 0.0, cc = 0.0;
    #pragma unroll
    for (int i = 0; i < 3; ++i) {
        const int p = s * SLABR + i * 256 + tid;
        if (p < PRI) {
            float2 ch = ws_ch[(unsigned)b * PRI + p];
            unsigned hb = __float_as_uint(ch.y);
            const bool pos = (hb >> 31) != 0;
            const unsigned key = pos ? 0x80000000u : f2k(ch.x);
            const float hlv = __uint_as_float(hb & 0x7fffffffu);
            if (pos || key > T) { aC += (double)ch.x; aH += (double)hlv; }
            if (key == T) {
                cc += 1.0;
                if (!pos) { tC += (double)ch.x; tH += (double)hlv; }
            }
        }
    }
    double v;
    v = blockReduce(aC, sred); if (tid == 0) sums[0 * GBLK + blockIdx.x] = v;
    v = blockReduce(aH, sred); if (tid == 0) sums[1 * GBLK + blockIdx.x] = v;
    v = blockReduce(tC, sred); if (tid == 0) sums[2 * GBLK + blockIdx.x] = v;
    v = blockReduce(tH, sred); if (tid == 0) sums[3 * GBLK + blockIdx.x] = v;
    v = blockReduce(cc, sred); if (tid == 0) cntT[blockIdx.x] = (int)(v + 0.5);
}

// Per batch: find cutoff slab from tie counts, scan it for the needed-th tie,
// add tie-negative partials, emit final (loss_c, loss_has_lp) for the batch.
__global__ __launch_bounds__(256) void k_cut(
    const float2* __restrict__ ws_ch, const unsigned* __restrict__ selT,
    const int* __restrict__ needed, const int* __restrict__ cntT,
    const double* __restrict__ sums, double* __restrict__ lossCH)
{
    const int b = blockIdx.x, tid = threadIdx.x;
    __shared__ double sred[4];
    __shared__ int scnt_s[32];
    __shared__ int s_sl, s_loc, s_found;
    __shared__ int wtot[4];
    const int need = needed[b];
    const unsigned T = selT[b];

    if (tid < 32) scnt_s[tid] = cntT[b * 32 + tid];
    __syncthreads();
    if (tid == 0) {
        int sl = 32, loc = 0, cum = 0;
        if (need > 0) {
            for (int s2 = 0; s2 < 32; ++s2) {
                int c2 = scnt_s[s2];
                if (cum + c2 >= need) { sl = s2; loc = need - cum; break; }
                cum += c2;
            }
        }
        s_sl = sl; s_loc = loc; s_found = -1;
    }
    __syncthreads();
    const int sl = s_sl, loc = s_loc;

    // base: all selected-core sums + tie-neg sums for slabs fully before sl
    double aC = 0.0, aH = 0.0;
    if (tid < 32) {
        aC = sums[0 * GBLK + b * 32 + tid] + (tid < sl ? sums[2 * GBLK + b * 32 + tid] : 0.0);
        aH = sums[1 * GBLK + b * 32 + tid] + (tid < sl ? sums[3 * GBLK + b * 32 + tid] : 0.0);
    }
    double totC = blockReduce(aC, sred);
    double totH = blockReduce(aH, sred);

    if (sl < 32) {
        // pass 1: find cutoff = global index of the loc-th key==T row in slab sl
        int run = 0;
        for (int i = 0; i < 3; ++i) {
            const int p = sl * SLABR + i * 256 + tid;
            bool eq = false;
            if (p < PRI) eq = (chkey(ws_ch[(unsigned)b * PRI + p]) == T);
            const unsigned long long m = __ballot(eq);
            const int lane = tid & 63, wid = tid >> 6;
            if (lane == 0) wtot[wid] = __popcll(m);
            const int mex = __popcll(m & ((1ull << lane) - 1ull));
            __syncthreads();
            int woff = 0;
            for (int w = 0; w < wid; ++w) woff += wtot[w];
            if (eq && (run + woff + mex + 1 == loc)) s_found = p;
            __syncthreads();
            run += wtot[0] + wtot[1] + wtot[2] + wtot[3];
            __syncthreads();
        }
        const int cutoff = s_found;
        // pass 2: tie-negative sums within slab sl with p <= cutoff
        double pC = 0.0, pH = 0.0;
        for (int i = 0; i < 3; ++i) {
            const int p = sl * SLABR + i * 256 + tid;
            if (p < PRI && p <= cutoff) {
                float2 ch = ws_ch[(unsigned)b * PRI + p];
                unsigned hb = __float_as_uint(ch.y);
                const bool pos = (hb >> 31) != 0;
                const unsigned key = pos ? 0x80000000u : f2k(ch.x);
                if (!pos && key == T) {
                    pC += (double)ch.x;
                    pH += (double)__uint_as_float(hb & 0x7fffffffu);
                }
            }
        }
        double v1 = blockReduce(pC, sred);
        double v2 = blockReduce(pH, sred);
        if (tid == 0) { totC += v1; totH += v2; }
    }
    if (tid == 0) { lossCH[b] = totC; lossCH[64 + b] = totH; }
}

// Sum partials, divide by N, emit 5 outputs.
__global__ __launch_bounds__(256) void k_final(
    const double* __restrict__ part, const int* __restrict__ numpos,
    const double* __restrict__ lossCH, float* __restrict__ out)
{
    __shared__ double sred[4];
    const int tid = threadIdx.x;
    double s[3];
    #pragma unroll
    for (int k = 0; k < 3; ++k) {
        double a = 0.0;
        for (int t = tid; t < GBLK; t += 256) a += part[k * GBLK + t];
        s[k] = blockReduce(a, sred);
    }
    double lc = (tid < BATCH) ? lossCH[tid] : 0.0;
    lc = blockReduce(lc, sred);
    double lh = (tid < BATCH) ? lossCH[64 + tid] : 0.0;
    lh = blockReduce(lh, sred);
    double n = (tid < BATCH) ? (double)numpos[tid] : 0.0;
    n = blockReduce(n, sred);
    if (tid == 0) {
        out[0] = (float)(s[0] / n);   // loss_l
        out[1] = (float)(lc / n);     // loss_c
        out[2] = (float)(s[1] / n);   // loss_size_lp
        out[3] = (float)(s[2] / n);   // loss_offset
        out[4] = (float)(lh / n);     // loss_has_lp
    }
}

extern "C" void kernel_launch(void* const* d_in, const int* in_sizes, int n_in,
                              void* d_out, int out_size, void* d_ws, size_t ws_size,
                              hipStream_t stream)
{
    const float* loc_data     = (const float*)d_in[0];
    const float* conf_data    = (const float*)d_in[1];
    const float* has_lp_data  = (const float*)d_in[2];
    const float* size_lp_data = (const float*)d_in[3];
    const float* offset_data  = (const float*)d_in[4];
    const float* loc_t        = (const float*)d_in[5];
    const int*   conf_t       = (const int*)d_in[6];
    const int*   has_lp_t     = (const int*)d_in[7];
    const float* size_lp_t    = (const float*)d_in[8];
    const float* offset_t     = (const float*)d_in[9];
    float* out = (float*)d_out;

    char* ws = (char*)d_ws;
    int* numpos      = (int*)(ws + 0);           // 64 int
    unsigned* selT   = (unsigned*)(ws + 256);    // 64 u32
    int* needed      = (int*)(ws + 512);         // 64 int
    unsigned* prefix = (unsigned*)(ws + 768);    // 64 u32
    int* rem         = (int*)(ws + 1024);        // 64 int
    int* cntT        = (int*)(ws + 1536);        // 2048 int (8 KB)
    double* part     = (double*)(ws + 16384);    // 3*2048 doubles (48 KB)
    double* sums     = (double*)(ws + 65536);    // 4*2048 doubles (64 KB)
    double* lossCH   = (double*)(ws + 131072);   // 128 doubles
    int* ghist1      = (int*)(ws + 132096);      // 64*4096 int (1 MB)
    int* ghist2      = (int*)(ws + 1180672);     // 64*1024 int (256 KB)
    int* ghist3      = (int*)(ws + 1442816);     // 64*1024 int (256 KB)
    float2* ws_ch    = (float2*)(ws + 1704960);  // NROWS float2 (~12.6 MB)

    hipMemsetAsync(ws, 0, 256, stream);                  // numpos
    hipMemsetAsync(ws + 132096, 0, 1572864, stream);     // ghist1..3

    k_main<<<GBLK, 256, 0, stream>>>(loc_data, conf_data, has_lp_data, size_lp_data,
                                     offset_data, loc_t, conf_t, has_lp_t,
                                     size_lp_t, offset_t, ws_ch, numpos, part, ghist1);
    k_pick0<<<BATCH, 256, 0, stream>>>(ghist1, numpos, prefix, rem, selT, needed);
    k_hist<20, 10><<<GBLK, 256, 0, stream>>>(ws_ch, prefix, ghist2);
    k_pickR<1><<<BATCH, 256, 0, stream>>>(ghist2, prefix, rem, selT, needed);
    k_hist<10, 0><<<GBLK, 256, 0, stream>>>(ws_ch, prefix, ghist3);
    k_pickR<2><<<BATCH, 256, 0, stream>>>(ghist3, prefix, rem, selT, needed);
    k_sel2<<<GBLK, 256, 0, stream>>>(ws_ch, selT, cntT, sums);
    k_cut<<<BATCH, 256, 0, stream>>>(ws_ch, selT, needed, cntT, sums, lossCH);
    k_final<<<1, 256, 0, stream>>>(part, numpos, lossCH, out);
}